// Round 2
// baseline (310.250 us; speedup 1.0000x reference)
//
#include <hip/hip_runtime.h>
#include <stdint.h>
#include <stddef.h>

// MASLoRALinear via concatenation identity:
//   hg[b,t,e*16+r] = SCALING * w[b,e] * (x @ As^T)[b,t,e,r]      (gate baked in)
//   out = [x_bf16 | hg] @ [W_base | Bcat]^T + b_base,  Bcat[o][e*16+r] = Bs[e,o,r]
// Weights are batch-shared -> M flattens to B*T=24000, weight tile L2-resident.
// LDS K-chunk XOR swizzle kills the 8-way ds_read_b128 bank conflict
// (global source addr per lane carries the swizzle; global_load_lds dst is forced).

#define B_ 16
#define T_ 1500
#define C_ 1024
#define O_ 1024
#define E_ 8
#define R_ 16
#define ER 128     // E*R
#define KK 1152    // C_ + ER
#define BT 24000   // B_*T_
#define SCALING 2.0f

typedef __bf16 bf16x8 __attribute__((ext_vector_type(8)));
typedef float f32x4 __attribute__((ext_vector_type(4)));
typedef unsigned short u16;

__device__ inline u16 f2bf(float f) {
  union { float f; unsigned u; } v; v.f = f;
  unsigned u = v.u;
  u += 0x7fff + ((u >> 16) & 1);  // RNE
  return (u16)(u >> 16);
}

#define GLL(gp, lp)                                                            \
  __builtin_amdgcn_global_load_lds(                                            \
      (const __attribute__((address_space(1))) void*)(gp),                     \
      (__attribute__((address_space(3))) void*)(lp), 16, 0, 0)

// ---------------- kernel 1: x fp32 -> bf16 into X' rows of KK ----------------
__global__ __launch_bounds__(256) void cvt_x(const float4* __restrict__ x,
                                             u16* __restrict__ xp) {
  int i = blockIdx.x * 256 + threadIdx.x;  // 6,144,000 threads (BT*C_/4)
  float4 v = x[i];
  int row = i >> 8;            // (i*4) / 1024
  int c = (i & 255) << 2;      // (i*4) % 1024
  ushort4 o;
  o.x = f2bf(v.x); o.y = f2bf(v.y); o.z = f2bf(v.z); o.w = f2bf(v.w);
  *(ushort4*)(xp + (size_t)row * KK + c) = o;
}

// ---------------- kernel 2: prep weights ----------------
// wp[o][0:1024]=bf16(W_base), wp[o][1024+e*16+r]=bf16(Bs[e,o,r]); ap=bf16(As flat).
__global__ __launch_bounds__(256) void prep_w(const float* __restrict__ Wb,
                                              const float* __restrict__ Bs,
                                              const float* __restrict__ As,
                                              u16* __restrict__ wp,
                                              u16* __restrict__ ap) {
  int idx = blockIdx.x * 256 + threadIdx.x;  // 1,310,720 total
  if (idx < O_ * KK) {
    int o = idx / KK;
    int k = idx - o * KK;
    float v;
    if (k < C_) {
      v = Wb[o * C_ + k];
    } else {
      int j = k - C_;
      v = Bs[((j >> 4) * O_ + o) * R_ + (j & 15)];
    }
    wp[idx] = f2bf(v);
  } else {
    int a = idx - O_ * KK;  // 131,072 elements of As
    ap[a] = f2bf(As[a]);
  }
}

// ---------------- kernel 3: h-GEMM + gate ----------------
// hg = (x_bf16 @ Asb^T) * (SCALING*w[b,e]) written into X'[:,1024:1152].
// M=24000 K=1024 N=128; 128x128 tile, BK=32, swizzled LDS.
__global__ __launch_bounds__(256) void h_gemm(u16* __restrict__ xp,
                                              const u16* __restrict__ ab,
                                              const float* __restrict__ w) {
  const int mt = blockIdx.x;  // 0..187
  const int tid = threadIdx.x, lane = tid & 63, wv = tid >> 6;
  const int wrow = wv & 1, wcol = wv >> 1, l15 = lane & 15, quad = lane >> 4;
  const int kx = quad ^ (l15 & 3) ^ ((l15 >> 2) & 3);  // lane-const read swizzle

  __shared__ u16 lA[128 * 32];
  __shared__ u16 lB[128 * 32];
  const u16* gA = xp + (size_t)mt * 128 * KK;

  f32x4 acc[4][4];
#pragma unroll
  for (int i = 0; i < 4; ++i)
#pragma unroll
    for (int j = 0; j < 4; ++j) acc[i][j] = (f32x4){0.f, 0.f, 0.f, 0.f};

  const int idx0 = tid, idx1 = 256 + tid;
  const int r0 = idx0 >> 2, kc0 = (idx0 & 3) ^ (r0 & 3) ^ ((r0 >> 2) & 3);
  const int r1 = idx1 >> 2, kc1 = (idx1 & 3) ^ (r1 & 3) ^ ((r1 >> 2) & 3);

  for (int kt = 0; kt < C_ / 32; ++kt) {
    const int k0 = kt * 32;
    GLL(gA + (size_t)r0 * KK + k0 + kc0 * 8, &lA[idx0 * 8]);
    GLL(gA + (size_t)r1 * KK + k0 + kc1 * 8, &lA[idx1 * 8]);
    GLL(ab + r0 * C_ + k0 + kc0 * 8, &lB[idx0 * 8]);
    GLL(ab + r1 * C_ + k0 + kc1 * 8, &lB[idx1 * 8]);
    __syncthreads();
    bf16x8 af[4], bfr[4];
#pragma unroll
    for (int i = 0; i < 4; ++i) {
      af[i] = *(const bf16x8*)&lA[(wrow * 64 + i * 16 + l15) * 32 + kx * 8];
      bfr[i] = *(const bf16x8*)&lB[(wcol * 64 + i * 16 + l15) * 32 + kx * 8];
    }
#pragma unroll
    for (int i = 0; i < 4; ++i)
#pragma unroll
      for (int j = 0; j < 4; ++j)
        acc[i][j] = __builtin_amdgcn_mfma_f32_16x16x32_bf16(af[i], bfr[j], acc[i][j], 0, 0, 0);
    __syncthreads();
  }

  // epilogue: col = wcol*64+j*16+l15 -> e = wcol*4+j (lane-uniform), r = l15
#pragma unroll
  for (int j = 0; j < 4; ++j) {
    const int col = wcol * 64 + j * 16 + l15;
    const int e = wcol * 4 + j;
#pragma unroll
    for (int i = 0; i < 4; ++i) {
#pragma unroll
      for (int rr = 0; rr < 4; ++rr) {
        const int row = mt * 128 + wrow * 64 + i * 16 + quad * 4 + rr;
        if (row < BT) {
          const int b = row / T_;  // compiler magic-mul
          xp[(size_t)row * KK + C_ + col] = f2bf(acc[i][j][rr] * (SCALING * w[b * E_ + e]));
        }
      }
    }
  }
}

// ---------------- kernel 4: main GEMM ----------------
// out[row][o] = X'[row,:] . W'[o,:] + b_base[o];  M=24000 K=1152 N=1024.
__global__ __launch_bounds__(256) void main_gemm(const u16* __restrict__ xp,
                                                 const u16* __restrict__ wp,
                                                 const float* __restrict__ bb,
                                                 float* __restrict__ out) {
  const int id = blockIdx.x;      // 0..1503
  const int nt = id & 7;          // id%8 -> per-XCD fixed N-tile (weight stays L2-hot)
  const int mt = id >> 3;         // 0..187
  const int tid = threadIdx.x, lane = tid & 63, wv = tid >> 6;
  const int wrow = wv & 1, wcol = wv >> 1, l15 = lane & 15, quad = lane >> 4;
  const int kx = quad ^ (l15 & 3) ^ ((l15 >> 2) & 3);

  __shared__ u16 lA[128 * 32];
  __shared__ u16 lB[128 * 32];
  const u16* gA = xp + (size_t)mt * 128 * KK;
  const u16* gB = wp + (size_t)nt * 128 * KK;

  f32x4 acc[4][4];
#pragma unroll
  for (int i = 0; i < 4; ++i)
#pragma unroll
    for (int j = 0; j < 4; ++j) acc[i][j] = (f32x4){0.f, 0.f, 0.f, 0.f};

  const int idx0 = tid, idx1 = 256 + tid;
  const int r0 = idx0 >> 2, kc0 = (idx0 & 3) ^ (r0 & 3) ^ ((r0 >> 2) & 3);
  const int r1 = idx1 >> 2, kc1 = (idx1 & 3) ^ (r1 & 3) ^ ((r1 >> 2) & 3);

  for (int kt = 0; kt < KK / 32; ++kt) {  // 36 iterations
    const int k0 = kt * 32;
    GLL(gA + (size_t)r0 * KK + k0 + kc0 * 8, &lA[idx0 * 8]);
    GLL(gA + (size_t)r1 * KK + k0 + kc1 * 8, &lA[idx1 * 8]);
    GLL(gB + (size_t)r0 * KK + k0 + kc0 * 8, &lB[idx0 * 8]);
    GLL(gB + (size_t)r1 * KK + k0 + kc1 * 8, &lB[idx1 * 8]);
    __syncthreads();
    bf16x8 af[4], bfr[4];
#pragma unroll
    for (int i = 0; i < 4; ++i) {
      af[i] = *(const bf16x8*)&lA[(wrow * 64 + i * 16 + l15) * 32 + kx * 8];
      bfr[i] = *(const bf16x8*)&lB[(wcol * 64 + i * 16 + l15) * 32 + kx * 8];
    }
#pragma unroll
    for (int i = 0; i < 4; ++i)
#pragma unroll
      for (int j = 0; j < 4; ++j)
        acc[i][j] = __builtin_amdgcn_mfma_f32_16x16x32_bf16(af[i], bfr[j], acc[i][j], 0, 0, 0);
    __syncthreads();
  }

#pragma unroll
  for (int j = 0; j < 4; ++j) {
    const int col = nt * 128 + wcol * 64 + j * 16 + l15;
    const float bias = bb[col];
#pragma unroll
    for (int i = 0; i < 4; ++i) {
#pragma unroll
      for (int rr = 0; rr < 4; ++rr) {
        const int row = mt * 128 + wrow * 64 + i * 16 + quad * 4 + rr;
        if (row < BT) out[(size_t)row * O_ + col] = acc[i][j][rr] + bias;
      }
    }
  }
}

extern "C" void kernel_launch(void* const* d_in, const int* in_sizes, int n_in,
                              void* d_out, int out_size, void* d_ws, size_t ws_size,
                              hipStream_t stream) {
  const float* x = (const float*)d_in[0];    // (16,1500,1024)
  const float* w = (const float*)d_in[1];    // (16,8)
  const float* Wb = (const float*)d_in[2];   // (1024,1024)
  const float* bb = (const float*)d_in[3];   // (1024,)
  const float* As = (const float*)d_in[4];   // (8,16,1024)
  const float* Bs = (const float*)d_in[5];   // (8,1024,16)
  float* out = (float*)d_out;                // (16,1500,1024) fp32

  // ws: X' (24000x1152 u16, 55.30 MB) | W' (1024x1152 u16, 2.36 MB) | Asb (128x1024 u16, 0.26 MB)
  // Tail M-tile staging over-reads (rows 24000..24063) land in W' region - allocated, masked.
  u16* xp = (u16*)d_ws;
  u16* wp = xp + (size_t)BT * KK;
  u16* ap = wp + (size_t)O_ * KK;

  prep_w<<<(O_ * KK + ER * C_) / 256, 256, 0, stream>>>(Wb, Bs, As, wp, ap);
  cvt_x<<<BT * C_ / 1024, 256, 0, stream>>>((const float4*)x, xp);
  h_gemm<<<188, 256, 0, stream>>>(xp, ap, w);
  main_gemm<<<1504, 256, 0, stream>>>(xp, wp, bb, out);
}

// Round 3
// 299.346 us; speedup vs baseline: 1.0364x; 1.0364x over previous
//
#include <hip/hip_runtime.h>
#include <stdint.h>
#include <stddef.h>

// MASLoRALinear via concatenation identity:
//   hg[b,t,e*16+r] = SCALING * w[b,e] * (x @ As^T)[b,t,e,r]      (gate baked in)
//   out = [x_bf16 | hg] @ [W_base | Bcat]^T + b_base
// Round 3: (a) XCD-affine block map in main_gemm (8 nt-blocks of one mt share an
// XCD -> A-tile L2-resident, FETCH 219->~80MB); (b) cvt_x+h_gemm fused into
// cvt_h (64-row tiles, 375 blocks, pad-40 ds_write LDS = conflict-free reads).

#define B_ 16
#define T_ 1500
#define C_ 1024
#define O_ 1024
#define E_ 8
#define R_ 16
#define ER 128     // E*R
#define KK 1152    // C_ + ER
#define BT 24000   // B_*T_  (= 375 * 64 exactly)
#define SCALING 2.0f

typedef __bf16 bf16x8 __attribute__((ext_vector_type(8)));
typedef float f32x4 __attribute__((ext_vector_type(4)));
typedef unsigned short u16;

__device__ inline u16 f2bf(float f) {
  union { float f; unsigned u; } v; v.f = f;
  unsigned u = v.u;
  u += 0x7fff + ((u >> 16) & 1);  // RNE
  return (u16)(u >> 16);
}

#define GLL(gp, lp)                                                            \
  __builtin_amdgcn_global_load_lds(                                            \
      (const __attribute__((address_space(1))) void*)(gp),                     \
      (__attribute__((address_space(3))) void*)(lp), 16, 0, 0)

// ---------------- kernel 1: prep weights ----------------
// wp[o][0:1024]=bf16(W_base), wp[o][1024+e*16+r]=bf16(Bs[e,o,r]); ap=bf16(As flat).
__global__ __launch_bounds__(256) void prep_w(const float* __restrict__ Wb,
                                              const float* __restrict__ Bs,
                                              const float* __restrict__ As,
                                              u16* __restrict__ wp,
                                              u16* __restrict__ ap) {
  int idx = blockIdx.x * 256 + threadIdx.x;
  if (idx < O_ * KK) {
    int o = idx / KK;
    int k = idx - o * KK;
    float v;
    if (k < C_) {
      v = Wb[o * C_ + k];
    } else {
      int j = k - C_;
      v = Bs[((j >> 4) * O_ + o) * R_ + (j & 15)];
    }
    wp[idx] = f2bf(v);
  } else {
    int a = idx - O_ * KK;  // 131,072 elements of As
    ap[a] = f2bf(As[a]);
  }
}

// ---------------- kernel 2: fused convert + h-GEMM + gate ----------------
// Per 64-row M-tile: stream x fp32, convert to bf16 in regs, ds_write into
// pad-40 LDS A (conflict-free b128 reads: bank step 20/row) AND store to
// X'[:,0:1024]; MFMA vs Asb (staged via GLL); epilogue writes gated hg into
// X'[:,1024:1152]. 375 blocks x 256 thr; waves 2x2, each 32x64 (acc[2][4]).
__global__ __launch_bounds__(256) void cvt_h(const float* __restrict__ x,
                                             const u16* __restrict__ ab,
                                             const float* __restrict__ w,
                                             u16* __restrict__ xp) {
  const int mt = blockIdx.x;  // 0..374 (exact: 375*64 = 24000)
  const int tid = threadIdx.x, lane = tid & 63, wv = tid >> 6;
  const int wrow = wv & 1, wcol = wv >> 1, l15 = lane & 15, quad = lane >> 4;
  const int kx = quad ^ (l15 & 3) ^ ((l15 >> 2) & 3);  // lB chunk-swizzle read pos

  __shared__ u16 lA[64 * 40];   // row stride 40 u16 = 80 B -> bank step 20
  __shared__ u16 lB[128 * 32];  // GLL-staged (layout forced)

  const size_t row0 = (size_t)mt * 64;

  f32x4 acc[2][4];
#pragma unroll
  for (int i = 0; i < 2; ++i)
#pragma unroll
    for (int j = 0; j < 4; ++j) acc[i][j] = (f32x4){0.f, 0.f, 0.f, 0.f};

  const int idx0 = tid, idx1 = 256 + tid;
  const int r0 = idx0 >> 2, kc0 = (idx0 & 3) ^ (r0 & 3) ^ ((r0 >> 2) & 3);
  const int r1 = idx1 >> 2, kc1 = (idx1 & 3) ^ (r1 & 3) ^ ((r1 >> 2) & 3);

  const int xr0 = tid >> 3;            // 0..31
  const int xr1 = xr0 + 32;            // 32..63
  const int xc = (tid & 7) * 4;        // 0,4,..,28

  for (int kt = 0; kt < C_ / 32; ++kt) {
    const int k0 = kt * 32;
    GLL(ab + r0 * C_ + k0 + kc0 * 8, &lB[idx0 * 8]);
    GLL(ab + r1 * C_ + k0 + kc1 * 8, &lB[idx1 * 8]);
    float4 v0 = *(const float4*)&x[(row0 + xr0) * C_ + k0 + xc];
    float4 v1 = *(const float4*)&x[(row0 + xr1) * C_ + k0 + xc];
    ushort4 o0, o1;
    o0.x = f2bf(v0.x); o0.y = f2bf(v0.y); o0.z = f2bf(v0.z); o0.w = f2bf(v0.w);
    o1.x = f2bf(v1.x); o1.y = f2bf(v1.y); o1.z = f2bf(v1.z); o1.w = f2bf(v1.w);
    *(ushort4*)&lA[xr0 * 40 + xc] = o0;
    *(ushort4*)&lA[xr1 * 40 + xc] = o1;
    *(ushort4*)&xp[(row0 + xr0) * KK + k0 + xc] = o0;
    *(ushort4*)&xp[(row0 + xr1) * KK + k0 + xc] = o1;
    __syncthreads();  // drains GLL (vmcnt) + ds_writes (lgkmcnt)
    bf16x8 af[2], bfr[4];
#pragma unroll
    for (int i = 0; i < 2; ++i)
      af[i] = *(const bf16x8*)&lA[(wrow * 32 + i * 16 + l15) * 40 + quad * 8];
#pragma unroll
    for (int j = 0; j < 4; ++j)
      bfr[j] = *(const bf16x8*)&lB[(wcol * 64 + j * 16 + l15) * 32 + kx * 8];
#pragma unroll
    for (int i = 0; i < 2; ++i)
#pragma unroll
      for (int j = 0; j < 4; ++j)
        acc[i][j] = __builtin_amdgcn_mfma_f32_16x16x32_bf16(af[i], bfr[j], acc[i][j], 0, 0, 0);
    __syncthreads();
  }

  // epilogue: col -> expert e = wcol*4+j (lane-uniform), rank r = l15
#pragma unroll
  for (int j = 0; j < 4; ++j) {
    const int col = wcol * 64 + j * 16 + l15;
    const int e = wcol * 4 + j;
#pragma unroll
    for (int i = 0; i < 2; ++i) {
#pragma unroll
      for (int rr = 0; rr < 4; ++rr) {
        const int row = mt * 64 + wrow * 32 + i * 16 + quad * 4 + rr;
        const int b = row / T_;
        xp[(size_t)row * KK + C_ + col] = f2bf(acc[i][j][rr] * (SCALING * w[b * E_ + e]));
      }
    }
  }
}

// ---------------- kernel 3: main GEMM ----------------
// out[row][o] = X'[row,:] . W'[o,:] + b_base[o];  M=24000 K=1152 N=1024.
// XCD-affine map: all 8 nt's of one mt share id%8 (same XCD, adjacent launch)
// -> A-tile fetched once per XCD; W' (2.3 MB) L2-resident per XCD.
__global__ __launch_bounds__(256) void main_gemm(const u16* __restrict__ xp,
                                                 const u16* __restrict__ wp,
                                                 const float* __restrict__ bb,
                                                 float* __restrict__ out) {
  const int id = blockIdx.x;                     // 0..1535
  const int mt = ((id >> 6) << 3) | (id & 7);    // 0..191
  const int nt = (id >> 3) & 7;                  // 0..7
  if (mt >= 188) return;                          // uniform early-exit (no barriers yet)
  const int tid = threadIdx.x, lane = tid & 63, wv = tid >> 6;
  const int wrow = wv & 1, wcol = wv >> 1, l15 = lane & 15, quad = lane >> 4;
  const int kx = quad ^ (l15 & 3) ^ ((l15 >> 2) & 3);

  __shared__ u16 lA[128 * 32];
  __shared__ u16 lB[128 * 32];
  const u16* gA = xp + (size_t)mt * 128 * KK;
  const u16* gB = wp + (size_t)nt * 128 * KK;

  f32x4 acc[4][4];
#pragma unroll
  for (int i = 0; i < 4; ++i)
#pragma unroll
    for (int j = 0; j < 4; ++j) acc[i][j] = (f32x4){0.f, 0.f, 0.f, 0.f};

  const int idx0 = tid, idx1 = 256 + tid;
  const int r0 = idx0 >> 2, kc0 = (idx0 & 3) ^ (r0 & 3) ^ ((r0 >> 2) & 3);
  const int r1 = idx1 >> 2, kc1 = (idx1 & 3) ^ (r1 & 3) ^ ((r1 >> 2) & 3);

  for (int kt = 0; kt < KK / 32; ++kt) {  // 36 iterations
    const int k0 = kt * 32;
    GLL(gA + (size_t)r0 * KK + k0 + kc0 * 8, &lA[idx0 * 8]);
    GLL(gA + (size_t)r1 * KK + k0 + kc1 * 8, &lA[idx1 * 8]);
    GLL(gB + (size_t)r0 * KK + k0 + kc0 * 8, &lB[idx0 * 8]);
    GLL(gB + (size_t)r1 * KK + k0 + kc1 * 8, &lB[idx1 * 8]);
    __syncthreads();
    bf16x8 af[4], bfr[4];
#pragma unroll
    for (int i = 0; i < 4; ++i) {
      af[i] = *(const bf16x8*)&lA[(wrow * 64 + i * 16 + l15) * 32 + kx * 8];
      bfr[i] = *(const bf16x8*)&lB[(wcol * 64 + i * 16 + l15) * 32 + kx * 8];
    }
#pragma unroll
    for (int i = 0; i < 4; ++i)
#pragma unroll
      for (int j = 0; j < 4; ++j)
        acc[i][j] = __builtin_amdgcn_mfma_f32_16x16x32_bf16(af[i], bfr[j], acc[i][j], 0, 0, 0);
    __syncthreads();
  }

#pragma unroll
  for (int j = 0; j < 4; ++j) {
    const int col = nt * 128 + wcol * 64 + j * 16 + l15;
    const float bias = bb[col];
#pragma unroll
    for (int i = 0; i < 4; ++i) {
#pragma unroll
      for (int rr = 0; rr < 4; ++rr) {
        const int row = mt * 128 + wrow * 64 + i * 16 + quad * 4 + rr;
        if (row < BT) out[(size_t)row * O_ + col] = acc[i][j][rr] + bias;
      }
    }
  }
}

extern "C" void kernel_launch(void* const* d_in, const int* in_sizes, int n_in,
                              void* d_out, int out_size, void* d_ws, size_t ws_size,
                              hipStream_t stream) {
  const float* x = (const float*)d_in[0];    // (16,1500,1024)
  const float* w = (const float*)d_in[1];    // (16,8)
  const float* Wb = (const float*)d_in[2];   // (1024,1024)
  const float* bb = (const float*)d_in[3];   // (1024,)
  const float* As = (const float*)d_in[4];   // (8,16,1024)
  const float* Bs = (const float*)d_in[5];   // (8,1024,16)
  float* out = (float*)d_out;                // (16,1500,1024) fp32

  // ws: X' (24000x1152 u16, 55.30 MB) | W' (1024x1152 u16, 2.36 MB) | Asb (128x1024 u16, 0.26 MB)
  // main_gemm mt=187 staging over-reads rows 24000..24063 -> land in W' region (allocated, masked).
  u16* xp = (u16*)d_ws;
  u16* wp = xp + (size_t)BT * KK;
  u16* ap = wp + (size_t)O_ * KK;

  prep_w<<<(O_ * KK + ER * C_) / 256, 256, 0, stream>>>(Wb, Bs, As, wp, ap);
  cvt_h<<<375, 256, 0, stream>>>(x, ap, w, xp);
  main_gemm<<<1536, 256, 0, stream>>>(xp, wp, bb, out);
}